// Round 3
// 692.662 us; speedup vs baseline: 1.3124x; 1.3124x over previous
//
#include <hip/hip_runtime.h>
#include <hip/hip_bf16.h>

typedef unsigned short u16;
typedef unsigned int   u32;
typedef __bf16 bfrag8 __attribute__((ext_vector_type(8)));
typedef float  ffrag4 __attribute__((ext_vector_type(4)));

#define DEVI __device__ __forceinline__

// ---- problem constants ----
constexpr int  NC  = 128;
constexpr int  NHW = 96 * 96;   // 9216
constexpr int  NS  = 576;       // 24*24 tokens
constexpr int  NDH = 32;        // head dim
constexpr int  BK  = 32;        // K-chunk (one mfma K)
constexpr int  BKP = 40;        // padded LDS row in u16 (80B, multiple of 16B)
constexpr int  KSPLIT = 8;      // k_fwd split-K factor (9216/8 = 1152, mult of 32)

constexpr long PB  = (long)NS * NC;   // 73728
constexpr long TOT = (long)8 * PB;    // 589824

// ---- workspace layout (u16 element offsets), bf16 intermediates ----
constexpr long OFF_XHr  = 0 * TOT;   // (dead — kept for layout stability)
constexpr long OFF_XHi  = 1 * TOT;
constexpr long OFF_Qr   = 2 * TOT;
constexpr long OFF_Qi   = 3 * TOT;
constexpr long OFF_Kr   = 4 * TOT;
constexpr long OFF_Ki   = 5 * TOT;
constexpr long OFF_Vr   = 6 * TOT;
constexpr long OFF_Vi   = 7 * TOT;
constexpr long OFF_VrT  = 8 * TOT;
constexpr long OFF_ViT  = 9 * TOT;
constexpr long OFF_Or   = 10 * TOT;
constexpr long OFF_Oi   = 11 * TOT;
constexpr long OFF_OHr  = 12 * TOT;
constexpr long OFF_OHi  = 13 * TOT;
constexpr long OFF_OHrT = 14 * TOT;
constexpr long OFF_OHiT = 15 * TOT;
constexpr long OFF_LG   = 16 * TOT;  // logits/probs: 32*576*576 = 18*TOT
// fp32 xhat accumulator (re then im, 16*PB floats = 4.7 MB) lives at the FRONT
// of the LG region: written by k_fwd (atomics), read by k_proj, then k_logits
// overwrites the region. XT reuses LG after attnv as before.
constexpr long OFF_XT   = 16 * TOT;  // x^T bf16 (hw,c) — reuses LG AFTER attnv
constexpr long OFF_XB   = 34 * TOT;  // x bf16 (b,c,hw) — lives here until k_inv
constexpr long OFF_XR   = 34 * TOT;  // x_rec / mixer / ln (b,hw,c) — written by k_inv
// total: 50*TOT*2 bytes ~= 59 MB

DEVI float bf2f(u16 x) { u32 u = ((u32)x) << 16; float f; __builtin_memcpy(&f, &u, 4); return f; }
DEVI u16   f2bf(float f) { u32 u; __builtin_memcpy(&u, &f, 4); u += 0x7fffu + ((u >> 16) & 1u); return (u16)(u >> 16); }
DEVI float gelu_f(float x) {   // JAX default gelu: tanh approximation
  float y = 0.7978845608028654f * (x + 0.044715f * x * x * x);
  float t = 1.0f - 2.0f / (__expf(2.0f * y) + 1.0f);  // stable tanh(y)
  return 0.5f * x * (1.0f + t);
}

// LDS row base with bank-group swizzle. INJECTIVITY: each row uses 32 of its
// 40 u16 slots; an offset pattern is safe iff off(r+1) >= off(r) - 8. The
// alternating 0/8 per 8-row group satisfies this exactly at wrap (-8 lands on
// the next row's base). It splits the mv in {0,8,16,24} TA-store row groups
// (row stride 80B == 0 mod 128B -> same bank) into two bank groups -> max
// 2-way conflict, which is free on CDNA4. Keeps 16B alignment for b128 ops.
DEVI int rofs(int r) { return r * BKP + ((r >> 3) & 1) * 8; }

// load 8 contiguous bf16 (as uint4)
DEVI uint4 ld8_bf(const u16* p) { return *(const uint4*)p; }
// load 8 contiguous fp32, round to bf16, pack into uint4
DEVI uint4 ld8_f32(const float* p) {
  float4 a = *(const float4*)p;
  float4 b = *(const float4*)(p + 4);
  u16 e[8] = {f2bf(a.x), f2bf(a.y), f2bf(a.z), f2bf(a.w),
              f2bf(b.x), f2bf(b.y), f2bf(b.z), f2bf(b.w)};
  uint4 r; __builtin_memcpy(&r, e, 16); return r;
}

struct GemmP {
  const u16*   A1; const u16*   A2;    // bf16 sources
  const u16*   B1; const u16*   B2;
  const float* A1f; const float* A2f;  // fp32 sources (used when AF32/BF32)
  const float* B1f; const float* B2f;
  int lda, ldb, K, negB2;
  u16* C; float* Cf; int ldc;
  float scale;
  const float* biasf;    // BIAS==1: per-row[m], BIAS==2: per-col[n]
  const float* cscalef;  // per-col scale (alpha)
  const u16*   aux;      // aux add (bf16, read at aux[n*ldaux+m]) then gelu
  int ldaux;
};

// C[m,n] = scale*(A1·B1 (+/-) A2·B2) [+bias][*cscale][+aux->gelu], fp32 acc.
// A "easy": elem(m,k) at A + m*lda + k (k contig). TA: elem(m,k) at A + k*lda + m.
// B always: elem(k,n) at B + n*ldb + k (k contig).
// OUTATOMIC: atomicAdd fp32 into Cf (split-K accumulation).
template <int BM, int BN, bool TA, bool DUAL, int BIAS, bool CS, bool AUXG,
          bool AF32, bool BF32, bool OUTF, bool OUTATOMIC>
DEVI void gemm_core(const GemmP p, int bx, int by) {
  __shared__ u16 As1[BM * BKP + 32];
  __shared__ u16 Bs1[BN * BKP + 32];
  __shared__ u16 As2[DUAL ? BM * BKP + 32 : 8];
  __shared__ u16 Bs2[DUAL ? BN * BKP + 32 : 8];

  const int tid  = threadIdx.x;
  const int lane = tid & 63;
  const int wave = tid >> 6;
  const int wm = wave >> 1, wn = wave & 1;
  constexpr int WM = BM / 2, WN = BN / 2, TM = WM / 16, TN = WN / 16;
  const int lm = lane & 15, lq = lane >> 4;
  const long m0 = (long)bx * BM;
  const long n0 = (long)by * BN;

  ffrag4 acc[TM][TN];
  const ffrag4 z4 = {0.f, 0.f, 0.f, 0.f};
#pragma unroll
  for (int a = 0; a < TM; a++)
#pragma unroll
    for (int b = 0; b < TN; b++) acc[a][b] = z4;

  for (int k0 = 0; k0 < p.K; k0 += BK) {
    if constexpr (!TA) {
      for (int i = tid; i < BM * (BK / 8); i += 256) {
        int m = i >> 2, kv = (i & 3) << 3;
        long off = (m0 + m) * p.lda + k0 + kv;
        uint4 v1 = AF32 ? ld8_f32(p.A1f + off) : ld8_bf(p.A1 + off);
        *(uint4*)&As1[rofs(m) + kv] = v1;
        if constexpr (DUAL) {
          uint4 v2 = AF32 ? ld8_f32(p.A2f + off) : ld8_bf(p.A2 + off);
          *(uint4*)&As2[rofs(m) + kv] = v2;
        }
      }
    } else {
      for (int i = tid; i < (BM / 8) * BK; i += 256) {
        int k = i / (BM / 8), mv = (i % (BM / 8)) * 8;
        long off = (long)(k0 + k) * p.lda + m0 + mv;
        uint4 t4 = AF32 ? ld8_f32(p.A1f + off) : ld8_bf(p.A1 + off);
        u16 e[8]; __builtin_memcpy(e, &t4, 16);
#pragma unroll
        for (int j = 0; j < 8; j++) As1[rofs(mv + j) + k] = e[j];
        if constexpr (DUAL) {
          uint4 t5 = AF32 ? ld8_f32(p.A2f + off) : ld8_bf(p.A2 + off);
          u16 e2[8]; __builtin_memcpy(e2, &t5, 16);
#pragma unroll
          for (int j = 0; j < 8; j++) As2[rofs(mv + j) + k] = e2[j];
        }
      }
    }
    for (int i = tid; i < BN * (BK / 8); i += 256) {
      int n = i >> 2, kv = (i & 3) << 3;
      long off = (n0 + n) * p.ldb + k0 + kv;
      uint4 v1 = BF32 ? ld8_f32(p.B1f + off) : ld8_bf(p.B1 + off);
      *(uint4*)&Bs1[rofs(n) + kv] = v1;
      if constexpr (DUAL) {
        uint4 v2 = BF32 ? ld8_f32(p.B2f + off) : ld8_bf(p.B2 + off);
        if (p.negB2) { v2.x ^= 0x80008000u; v2.y ^= 0x80008000u; v2.z ^= 0x80008000u; v2.w ^= 0x80008000u; }
        *(uint4*)&Bs2[rofs(n) + kv] = v2;
      }
    }
    __syncthreads();
    {
      bfrag8 af[TM], bfv[TN];
#pragma unroll
      for (int t = 0; t < TM; t++) af[t] = *(const bfrag8*)&As1[rofs(wm * WM + t * 16 + lm) + lq * 8];
#pragma unroll
      for (int t = 0; t < TN; t++) bfv[t] = *(const bfrag8*)&Bs1[rofs(wn * WN + t * 16 + lm) + lq * 8];
#pragma unroll
      for (int a = 0; a < TM; a++)
#pragma unroll
        for (int b = 0; b < TN; b++)
          acc[a][b] = __builtin_amdgcn_mfma_f32_16x16x32_bf16(af[a], bfv[b], acc[a][b], 0, 0, 0);
      if constexpr (DUAL) {
        bfrag8 af2[TM], bfv2[TN];
#pragma unroll
        for (int t = 0; t < TM; t++) af2[t] = *(const bfrag8*)&As2[rofs(wm * WM + t * 16 + lm) + lq * 8];
#pragma unroll
        for (int t = 0; t < TN; t++) bfv2[t] = *(const bfrag8*)&Bs2[rofs(wn * WN + t * 16 + lm) + lq * 8];
#pragma unroll
        for (int a = 0; a < TM; a++)
#pragma unroll
          for (int b = 0; b < TN; b++)
            acc[a][b] = __builtin_amdgcn_mfma_f32_16x16x32_bf16(af2[a], bfv2[b], acc[a][b], 0, 0, 0);
      }
    }
    __syncthreads();
  }

  // epilogue: C/D layout col = lane&15, row = (lane>>4)*4 + r
#pragma unroll
  for (int a = 0; a < TM; a++) {
#pragma unroll
    for (int b = 0; b < TN; b++) {
      const long mb = m0 + wm * WM + a * 16 + lq * 4;
      const long n  = n0 + wn * WN + b * 16 + lm;
      float csv = 1.f, cbv = 0.f;
      if constexpr (CS)        csv = p.cscalef[n];
      if constexpr (BIAS == 2) cbv = p.biasf[n];
      uint2 axv; axv.x = 0u; axv.y = 0u;
      if constexpr (AUXG) axv = *(const uint2*)(p.aux + n * p.ldaux + mb);
      const u16* auxp = (const u16*)&axv;
#pragma unroll
      for (int r = 0; r < 4; r++) {
        float v = acc[a][b][r] * p.scale;
        if constexpr (CS)        v *= csv;
        if constexpr (BIAS == 1) v += p.biasf[mb + r];
        if constexpr (BIAS == 2) v += cbv;
        if constexpr (AUXG) { v += bf2f(auxp[r]); v = gelu_f(v); }
        if constexpr (OUTATOMIC) unsafeAtomicAdd(&p.Cf[(mb + r) * p.ldc + n], v);
        else if constexpr (OUTF) p.Cf[(mb + r) * p.ldc + n] = v;
        else                     p.C [(mb + r) * p.ldc + n] = f2bf(v);
      }
    }
  }
}

// ---- stage kernels ----

// zero fp32 buffer (float4 stores); exact grid, no tail
__global__ void __launch_bounds__(256) k_zero(float* __restrict__ p, long n4) {
  long i = (long)blockIdx.x * 256 + threadIdx.x;
  if (i < n4) *(float4*)(p + i * 4) = make_float4(0.f, 0.f, 0.f, 0.f);
}

// fp32 -> bf16 elementwise (4 at a time)
__global__ void __launch_bounds__(256) k_cvt(const float* __restrict__ in, u16* __restrict__ out, long n4) {
  long stride = (long)gridDim.x * 256;
  for (long i = (long)blockIdx.x * 256 + threadIdx.x; i < n4; i += stride) {
    float4 f = *(const float4*)(in + i * 4);
    u16 e[4] = {f2bf(f.x), f2bf(f.y), f2bf(f.z), f2bf(f.w)};
    uint2 r; __builtin_memcpy(&r, e, 8);
    *(uint2*)(out + i * 4) = r;
  }
}

// xhat[s,c] = sum_hw basis[hw,s] * x[c,hw]   (z: b*2+part); basis fp32, x bf16(XB)
// split-K over blockIdx.y (KSPLIT chunks), fp32 atomic accumulation into xhf.
__global__ void __launch_bounds__(256) k_fwd(const u16* __restrict__ ws_in, const float* __restrict__ bre,
                                             const float* __restrict__ bim, float* __restrict__ xhf) {
  const int z = blockIdx.z, b = z >> 1, part = z & 1;
  const long kbase = (long)blockIdx.y * (NHW / KSPLIT);
  GemmP p{};
  p.A1f = (part ? bim : bre) + (long)b * NHW * NS + kbase * NS;  // TA: elem(s,hw) at A + hw*NS + s
  p.B1  = ws_in + OFF_XB + (long)b * NC * NHW + kbase;           // elem(hw,c) at B + c*NHW + hw
  p.lda = NS; p.ldb = NHW; p.K = NHW / KSPLIT; p.scale = 1.f;
  p.Cf = xhf + (part ? (long)8 * PB : 0) + (long)b * PB; p.ldc = NC;
  gemm_core<32, 128, true, false, 0, false, false, true, false, true, true>(p, blockIdx.x, 0);
}

// q/k/v complex projections: z = b*6 + proj*2 + part; weights fp32, xhat fp32
__global__ void __launch_bounds__(256) k_proj(u16* __restrict__ ws, const float* __restrict__ xhf,
                                              const float* __restrict__ awr,
                                              const float* __restrict__ awi, const float* __restrict__ abr,
                                              const float* __restrict__ abi) {
  const int z = blockIdx.z;
  const int b = z / 6, rr = z % 6, pj = rr >> 1, part = rr & 1;
  GemmP p{};
  p.A1f = xhf + (long)b * PB;                 // xhat real (fp32)
  p.A2f = xhf + (long)8 * PB + (long)b * PB;  // xhat imag (fp32)
  p.lda = NC;
  const float* Wr = awr + (long)pj * NC * NC;
  const float* Wi = awi + (long)pj * NC * NC;
  if (part == 0) { p.B1f = Wr; p.B2f = Wi; p.negB2 = 1; p.biasf = abr + pj * NC; }  // re: tr*Wr - ti*Wi
  else           { p.B1f = Wi; p.B2f = Wr; p.negB2 = 0; p.biasf = abi + pj * NC; }  // im: tr*Wi + ti*Wr
  p.ldb = NC; p.K = NC; p.scale = 1.f;
  p.C = ws + (2 + 2 * pj + part) * TOT + (long)b * PB; p.ldc = NC;
  gemm_core<32, 128, false, true, 2, false, false, true, true, false, false>(p, blockIdx.x, blockIdx.y);
}

// logits[s,t] = (qr.kr + qi.ki)/sqrt(32), z = b*4+h  (all bf16)
__global__ void __launch_bounds__(256) k_logits(u16* __restrict__ ws) {
  const int z = blockIdx.z, b = z >> 2, h = z & 3;
  const long base = (long)b * PB + h * NDH;
  GemmP p{};
  p.A1 = ws + OFF_Qr + base; p.A2 = ws + OFF_Qi + base; p.lda = NC;
  p.B1 = ws + OFF_Kr + base; p.B2 = ws + OFF_Ki + base; p.ldb = NC;
  p.negB2 = 0; p.K = NDH;
  p.scale = 0.17677669529663687f;
  p.C = ws + OFF_LG + (long)z * NS * NS; p.ldc = NS;
  gemm_core<64, 64, false, true, 0, false, false, false, false, false, false>(p, blockIdx.x, blockIdx.y);
}

// in-place row softmax over 576 cols, one wave per row
__global__ void __launch_bounds__(64) k_softmax(u16* __restrict__ lg) {
  u16* pr = lg + (long)blockIdx.x * NS;
  const int lane = threadIdx.x;
  float v[9];
#pragma unroll
  for (int i = 0; i < 9; i++) v[i] = bf2f(pr[lane + i * 64]);
  float mx = v[0];
#pragma unroll
  for (int i = 1; i < 9; i++) mx = fmaxf(mx, v[i]);
  for (int o = 32; o >= 1; o >>= 1) mx = fmaxf(mx, __shfl_xor(mx, o, 64));
  float s = 0.f;
#pragma unroll
  for (int i = 0; i < 9; i++) { v[i] = __expf(v[i] - mx); s += v[i]; }
  for (int o = 32; o >= 1; o >>= 1) s += __shfl_xor(s, o, 64);
  float inv = 1.f / s;
#pragma unroll
  for (int i = 0; i < 9; i++) pr[lane + i * 64] = f2bf(v[i] * inv);
}

// tiled bf16 transpose: (slab,R,C) -> (slab,C,R); R,C multiples of 32
__global__ void __launch_bounds__(256) k_transp(const u16* __restrict__ in, u16* __restrict__ out,
                                                int R, int Ccols) {
  __shared__ u16 t[32][33];
  const long slab = blockIdx.z;
  const u16* pin = in + slab * (long)R * Ccols;
  u16* pout = out + slab * (long)R * Ccols;
  const int r0 = blockIdx.x * 32, c0 = blockIdx.y * 32;
  const int j = threadIdx.x & 31, i0 = threadIdx.x >> 5;
#pragma unroll
  for (int ii = 0; ii < 4; ii++) { int i = i0 + ii * 8; t[i][j] = pin[(long)(r0 + i) * Ccols + (c0 + j)]; }
  __syncthreads();
#pragma unroll
  for (int ii = 0; ii < 4; ii++) { int i = i0 + ii * 8; pout[(long)(c0 + i) * R + (r0 + j)] = t[j][i]; }
}

// o[s,d] = sum_t P[s,t]*V^T[d,t], z = (b*4+h)*2+part (bf16)
__global__ void __launch_bounds__(256) k_attnv(u16* __restrict__ ws) {
  const int z = blockIdx.z, zz = z >> 1, part = z & 1;
  const int b = zz >> 2, h = zz & 3;
  GemmP p{};
  p.A1 = ws + OFF_LG + (long)zz * NS * NS; p.lda = NS;
  p.B1 = ws + (part ? OFF_ViT : OFF_VrT) + (long)b * NC * NS + (long)h * NDH * NS; p.ldb = NS;
  p.K = NS; p.scale = 1.f;
  p.C = ws + (part ? OFF_Oi : OFF_Or) + (long)b * PB + h * NDH; p.ldc = NC;
  gemm_core<32, 32, false, false, 0, false, false, false, false, false, false>(p, blockIdx.x, blockIdx.y);
}

// o-projection (index 3), z = b*2+part; weights fp32
__global__ void __launch_bounds__(256) k_oproj(u16* __restrict__ ws, const float* __restrict__ awr,
                                               const float* __restrict__ awi, const float* __restrict__ abr,
                                               const float* __restrict__ abi) {
  const int z = blockIdx.z, b = z >> 1, part = z & 1;
  GemmP p{};
  p.A1 = ws + OFF_Or + (long)b * PB; p.A2 = ws + OFF_Oi + (long)b * PB; p.lda = NC;
  const float* Wr = awr + 3l * NC * NC;
  const float* Wi = awi + 3l * NC * NC;
  if (part == 0) { p.B1f = Wr; p.B2f = Wi; p.negB2 = 1; p.biasf = abr + 3 * NC; }
  else           { p.B1f = Wi; p.B2f = Wr; p.negB2 = 0; p.biasf = abi + 3 * NC; }
  p.ldb = NC; p.K = NC; p.scale = 1.f;
  p.C = ws + (part ? OFF_OHi : OFF_OHr) + (long)b * PB; p.ldc = NC;
  gemm_core<32, 128, false, true, 2, false, false, false, true, false, false>(p, blockIdx.x, blockIdx.y);
}

// x_rec[hw,c] = (sum_s ohr[s,c]*br[hw,s] + ohi[s,c]*bi[hw,s]) * alpha[c], z = b; basis fp32
__global__ void __launch_bounds__(256) k_inv(u16* __restrict__ ws, const float* __restrict__ bre,
                                             const float* __restrict__ bim, const float* __restrict__ alpha) {
  const int b = blockIdx.z;
  GemmP p{};
  p.A1f = bre + (long)b * NHW * NS; p.A2f = bim + (long)b * NHW * NS; p.lda = NS;
  p.B1 = ws + OFF_OHrT + (long)b * NC * NS; p.B2 = ws + OFF_OHiT + (long)b * NC * NS; p.ldb = NS;
  p.negB2 = 0; p.K = NS; p.scale = 1.f;
  p.cscalef = alpha;
  p.C = ws + OFF_XR + (long)b * NHW * NC; p.ldc = NC;
  gemm_core<64, 128, false, true, 0, true, false, true, false, false, false>(p, blockIdx.x, blockIdx.y);
}

// mixer: y[hw,co] = sum_c xr[hw,c]*W[co,c] + mb[co]  (in-place over XR, z = b); W fp32
// safe in place: each block reads exactly the A rows it writes (n covers full NC).
__global__ void __launch_bounds__(256) k_mixer(u16* __restrict__ ws, const float* __restrict__ mw,
                                               const float* __restrict__ mb) {
  const int b = blockIdx.z;
  GemmP p{};
  p.A1 = ws + OFF_XR + (long)b * NHW * NC; p.lda = NC;
  p.B1f = mw; p.ldb = NC;
  p.K = NC; p.scale = 1.f; p.biasf = mb;
  p.C = ws + OFF_XR + (long)b * NHW * NC; p.ldc = NC;
  gemm_core<64, 128, false, false, 2, false, false, false, true, false, false>(p, blockIdx.x, blockIdx.y);
}

// layernorm(c) + gelu, in place; one wave per 128-col row, 4 rows/block
__global__ void __launch_bounds__(256) k_ln(u16* __restrict__ y, const float* __restrict__ g,
                                            const float* __restrict__ be) {
  const long row = (long)blockIdx.x * 4 + (threadIdx.x >> 6);
  const int lane = threadIdx.x & 63;
  u16* pr = y + row * NC;
  float a = bf2f(pr[lane]), b = bf2f(pr[lane + 64]);
  float s = a + b;
  for (int o = 32; o >= 1; o >>= 1) s += __shfl_xor(s, o, 64);
  float mu = s * (1.f / 128.f);
  float da = a - mu, db = b - mu;
  float q = da * da + db * db;
  for (int o = 32; o >= 1; o >>= 1) q += __shfl_xor(q, o, 64);
  float r = rsqrtf(q * (1.f / 128.f) + 1e-5f);
  float o1 = da * r * g[lane] + be[lane];
  float o2 = db * r * g[lane + 64] + be[lane + 64];
  pr[lane] = f2bf(gelu_f(o1));
  pr[lane + 64] = f2bf(gelu_f(o2));
}

// out[co,hw] = gelu( y[hw,co] + sum_c sw[co,c]*xT[hw,c] + sb[co] ), z = b; sw fp32, out fp32
__global__ void __launch_bounds__(256) k_final(const u16* __restrict__ ws, const float* __restrict__ sw,
                                               const float* __restrict__ sb, float* __restrict__ out) {
  const int b = blockIdx.z;
  GemmP p{};
  p.A1f = sw; p.lda = NC;
  p.B1 = ws + OFF_XT + (long)b * NHW * NC; p.ldb = NC;
  p.K = NC; p.scale = 1.f;
  p.biasf = sb;                                            // row bias (per co)
  p.aux = ws + OFF_XR + (long)b * NHW * NC; p.ldaux = NC;  // y[hw,co] read transposed (bf16)
  p.Cf = out + (long)b * NC * NHW; p.ldc = NHW;
  gemm_core<128, 64, false, false, 1, false, true, true, false, true, false>(p, blockIdx.x, blockIdx.y);
}

extern "C" void kernel_launch(void* const* d_in, const int* in_sizes, int n_in,
                              void* d_out, int out_size, void* d_ws, size_t ws_size,
                              hipStream_t stream) {
  (void)in_sizes; (void)n_in; (void)out_size; (void)ws_size;
  const float* x    = (const float*)d_in[0];
  const float* bre  = (const float*)d_in[1];
  const float* bim  = (const float*)d_in[2];
  const float* awr  = (const float*)d_in[3];
  const float* awi  = (const float*)d_in[4];
  const float* abr  = (const float*)d_in[5];
  const float* abi  = (const float*)d_in[6];
  const float* alp  = (const float*)d_in[7];
  const float* mw   = (const float*)d_in[8];
  const float* mbp  = (const float*)d_in[9];
  const float* ng   = (const float*)d_in[10];
  const float* nbta = (const float*)d_in[11];
  const float* sw   = (const float*)d_in[12];
  const float* sb   = (const float*)d_in[13];
  u16*   ws  = (u16*)d_ws;
  float* xhf = (float*)(ws + OFF_LG);   // fp32 xhat accumulator (16*PB floats)
  float* out = (float*)d_out;
  const dim3 T256(256);

  k_zero   <<<dim3(1152),      T256,    0, stream>>>(xhf, (long)16 * PB / 4);
  k_cvt    <<<dim3(1024),      T256,    0, stream>>>(x, ws + OFF_XB, (long)8 * NC * NHW / 4);
  k_fwd    <<<dim3(18, KSPLIT, 16), T256, 0, stream>>>(ws, bre, bim, xhf);
  k_proj   <<<dim3(18, 1, 48), T256,    0, stream>>>(ws, xhf, awr, awi, abr, abi);
  k_logits <<<dim3(9, 9, 32),  T256,    0, stream>>>(ws);
  k_softmax<<<dim3(32 * NS),   dim3(64),0, stream>>>(ws + OFF_LG);
  k_transp <<<dim3(18, 4, 16), T256,    0, stream>>>(ws + OFF_Vr, ws + OFF_VrT, NS, NC);
  k_attnv  <<<dim3(18, 1, 64), T256,    0, stream>>>(ws);
  k_transp <<<dim3(4, 288, 8), T256,    0, stream>>>(ws + OFF_XB, ws + OFF_XT, NC, NHW);  // after attnv: LG dead
  k_oproj  <<<dim3(18, 1, 16), T256,    0, stream>>>(ws, awr, awi, abr, abi);
  k_transp <<<dim3(18, 4, 16), T256,    0, stream>>>(ws + OFF_OHr, ws + OFF_OHrT, NS, NC);
  k_inv    <<<dim3(144, 1, 8), T256,    0, stream>>>(ws, bre, bim, alp);
  k_mixer  <<<dim3(144, 1, 8), T256,    0, stream>>>(ws, mw, mbp);
  k_ln     <<<dim3(18432),     T256,    0, stream>>>(ws + OFF_XR, ng, nbta);
  k_final  <<<dim3(1, 144, 8), T256,    0, stream>>>(ws, sw, sb, out);
}

// Round 4
// 662.314 us; speedup vs baseline: 1.3725x; 1.0458x over previous
//
#include <hip/hip_runtime.h>
#include <hip/hip_bf16.h>

typedef unsigned short u16;
typedef unsigned int   u32;
typedef __bf16 bfrag8 __attribute__((ext_vector_type(8)));
typedef float  ffrag4 __attribute__((ext_vector_type(4)));

#define DEVI __device__ __forceinline__

// ---- problem constants ----
constexpr int  NC  = 128;
constexpr int  NHW = 96 * 96;   // 9216
constexpr int  NS  = 576;       // 24*24 tokens
constexpr int  NDH = 32;        // head dim
constexpr int  KSPLIT = 8;      // k_fwd split-K factor (9216/8 = 1152, mult of 64)

constexpr long PB  = (long)NS * NC;   // 73728
constexpr long TOT = (long)8 * PB;    // 589824

// ---- workspace layout (u16 element offsets), bf16 intermediates ----
constexpr long OFF_XHr  = 0 * TOT;   // (dead — kept for layout stability)
constexpr long OFF_XHi  = 1 * TOT;
constexpr long OFF_Qr   = 2 * TOT;
constexpr long OFF_Qi   = 3 * TOT;
constexpr long OFF_Kr   = 4 * TOT;
constexpr long OFF_Ki   = 5 * TOT;
constexpr long OFF_Vr   = 6 * TOT;
constexpr long OFF_Vi   = 7 * TOT;
constexpr long OFF_VrT  = 8 * TOT;
constexpr long OFF_ViT  = 9 * TOT;
constexpr long OFF_Or   = 10 * TOT;
constexpr long OFF_Oi   = 11 * TOT;
constexpr long OFF_OHr  = 12 * TOT;
constexpr long OFF_OHi  = 13 * TOT;
constexpr long OFF_OHrT = 14 * TOT;
constexpr long OFF_OHiT = 15 * TOT;
constexpr long OFF_LG   = 16 * TOT;  // logits/probs: 32*576*576 = 18*TOT
// fp32 xhat accumulator (re then im, 16*PB floats = 4.7 MB) lives at the FRONT
// of the LG region: written by k_fwd (atomics), read by k_proj, then k_logits
// overwrites the region. XT reuses LG after attnv as before.
constexpr long OFF_XT   = 16 * TOT;  // x^T bf16 (hw,c) — reuses LG AFTER attnv
constexpr long OFF_XB   = 34 * TOT;  // x bf16 (b,c,hw) — lives here until k_inv
constexpr long OFF_XR   = 34 * TOT;  // x_rec / mixer / ln (b,hw,c) — written by k_inv
// total: 50*TOT*2 bytes ~= 59 MB

DEVI float bf2f(u16 x) { u32 u = ((u32)x) << 16; float f; __builtin_memcpy(&f, &u, 4); return f; }
DEVI u16   f2bf(float f) { u32 u; __builtin_memcpy(&u, &f, 4); u += 0x7fffu + ((u >> 16) & 1u); return (u16)(u >> 16); }
DEVI float gelu_f(float x) {   // JAX default gelu: tanh approximation
  float y = 0.7978845608028654f * (x + 0.044715f * x * x * x);
  float t = 1.0f - 2.0f / (__expf(2.0f * y) + 1.0f);  // stable tanh(y)
  return 0.5f * x * (1.0f + t);
}

// load 8 contiguous bf16 (as uint4)
DEVI uint4 ld8_bf(const u16* p) { return *(const uint4*)p; }
// load 8 contiguous fp32, round to bf16 (native cast -> v_cvt_pk_bf16_f32, RNE),
// pack into uint4
DEVI uint4 ld8_f32(const float* p) {
  float4 a = *(const float4*)p;
  float4 b = *(const float4*)(p + 4);
  __bf16 e[8] = {(__bf16)a.x, (__bf16)a.y, (__bf16)a.z, (__bf16)a.w,
                 (__bf16)b.x, (__bf16)b.y, (__bf16)b.z, (__bf16)b.w};
  uint4 r; __builtin_memcpy(&r, e, 16); return r;
}

struct GemmP {
  const u16*   A1; const u16*   A2;    // bf16 sources
  const u16*   B1; const u16*   B2;
  const float* A1f; const float* A2f;  // fp32 sources (used when AF32/BF32)
  const float* B1f; const float* B2f;
  int lda, ldb, K, negB2;
  u16* C; float* Cf; int ldc;
  float scale;
  const float* biasf;    // BIAS==1: per-row[m], BIAS==2: per-col[n]
  const float* cscalef;  // per-col scale (alpha)
  const u16*   aux;      // aux add (bf16, read at aux[n*ldaux+m]) then gelu
  int ldaux;
};

// C[m,n] = scale*(A1·B1 (+/-) A2·B2) [+bias][*cscale][+aux->gelu], fp32 acc.
// A "easy": elem(m,k) at A + m*lda + k (k contig). TA: elem(m,k) at A + k*lda + m.
// B always: elem(k,n) at B + n*ldb + k (k contig).
// BKT: K-chunk per LDS stage (multiple of 32; p.K must be a multiple of BKT).
// OUTATOMIC: atomicAdd fp32 into Cf (split-K accumulation).
// LDS row swizzle: row r at r*BKPt + ((r>>3)&1)*8 (u16). INJECTIVE: row span is
// BKT of BKT+8 slots; offset drop at group wrap is -8 == pad. Splits the
// mv in {0,8,16,24} TA-store row groups into two bank sets (residual 4-way).
template <int BM, int BN, int BKT, bool TA, bool DUAL, int BIAS, bool CS, bool AUXG,
          bool AF32, bool BF32, bool OUTF, bool OUTATOMIC>
DEVI void gemm_core(const GemmP p, int bx, int by) {
  constexpr int BKPt = BKT + 8;
  __shared__ u16 As1[BM * BKPt + 32];
  __shared__ u16 Bs1[BN * BKPt + 32];
  __shared__ u16 As2[DUAL ? BM * BKPt + 32 : 8];
  __shared__ u16 Bs2[DUAL ? BN * BKPt + 32 : 8];

  const int tid  = threadIdx.x;
  const int lane = tid & 63;
  const int wave = tid >> 6;
  const int wm = wave >> 1, wn = wave & 1;
  constexpr int WM = BM / 2, WN = BN / 2, TM = WM / 16, TN = WN / 16;
  const int lm = lane & 15, lq = lane >> 4;
  const long m0 = (long)bx * BM;
  const long n0 = (long)by * BN;

  auto rofs = [](int r) { return r * BKPt + ((r >> 3) & 1) * 8; };

  ffrag4 acc[TM][TN];
  const ffrag4 z4 = {0.f, 0.f, 0.f, 0.f};
#pragma unroll
  for (int a = 0; a < TM; a++)
#pragma unroll
    for (int b = 0; b < TN; b++) acc[a][b] = z4;

  for (int k0 = 0; k0 < p.K; k0 += BKT) {
    if constexpr (!TA) {
      constexpr int KV = BKT / 8;
      for (int i = tid; i < BM * KV; i += 256) {
        int m = i / KV, kv = (i % KV) * 8;
        long off = (m0 + m) * p.lda + k0 + kv;
        uint4 v1 = AF32 ? ld8_f32(p.A1f + off) : ld8_bf(p.A1 + off);
        *(uint4*)&As1[rofs(m) + kv] = v1;
        if constexpr (DUAL) {
          uint4 v2 = AF32 ? ld8_f32(p.A2f + off) : ld8_bf(p.A2 + off);
          *(uint4*)&As2[rofs(m) + kv] = v2;
        }
      }
    } else {
      constexpr int MV = BM / 8;
      for (int i = tid; i < MV * BKT; i += 256) {
        int k = i / MV, mv = (i % MV) * 8;
        long off = (long)(k0 + k) * p.lda + m0 + mv;
        uint4 t4 = AF32 ? ld8_f32(p.A1f + off) : ld8_bf(p.A1 + off);
        u16 e[8]; __builtin_memcpy(e, &t4, 16);
#pragma unroll
        for (int j = 0; j < 8; j++) As1[rofs(mv + j) + k] = e[j];
        if constexpr (DUAL) {
          uint4 t5 = AF32 ? ld8_f32(p.A2f + off) : ld8_bf(p.A2 + off);
          u16 e2[8]; __builtin_memcpy(e2, &t5, 16);
#pragma unroll
          for (int j = 0; j < 8; j++) As2[rofs(mv + j) + k] = e2[j];
        }
      }
    }
    {
      constexpr int KV = BKT / 8;
      for (int i = tid; i < BN * KV; i += 256) {
        int n = i / KV, kv = (i % KV) * 8;
        long off = (n0 + n) * p.ldb + k0 + kv;
        uint4 v1 = BF32 ? ld8_f32(p.B1f + off) : ld8_bf(p.B1 + off);
        *(uint4*)&Bs1[rofs(n) + kv] = v1;
        if constexpr (DUAL) {
          uint4 v2 = BF32 ? ld8_f32(p.B2f + off) : ld8_bf(p.B2 + off);
          if (p.negB2) { v2.x ^= 0x80008000u; v2.y ^= 0x80008000u; v2.z ^= 0x80008000u; v2.w ^= 0x80008000u; }
          *(uint4*)&Bs2[rofs(n) + kv] = v2;
        }
      }
    }
    __syncthreads();
#pragma unroll
    for (int kk = 0; kk < BKT; kk += 32) {
      bfrag8 af[TM], bfv[TN];
#pragma unroll
      for (int t = 0; t < TM; t++) af[t] = *(const bfrag8*)&As1[rofs(wm * WM + t * 16 + lm) + kk + lq * 8];
#pragma unroll
      for (int t = 0; t < TN; t++) bfv[t] = *(const bfrag8*)&Bs1[rofs(wn * WN + t * 16 + lm) + kk + lq * 8];
#pragma unroll
      for (int a = 0; a < TM; a++)
#pragma unroll
        for (int b = 0; b < TN; b++)
          acc[a][b] = __builtin_amdgcn_mfma_f32_16x16x32_bf16(af[a], bfv[b], acc[a][b], 0, 0, 0);
      if constexpr (DUAL) {
        bfrag8 af2[TM], bfv2[TN];
#pragma unroll
        for (int t = 0; t < TM; t++) af2[t] = *(const bfrag8*)&As2[rofs(wm * WM + t * 16 + lm) + kk + lq * 8];
#pragma unroll
        for (int t = 0; t < TN; t++) bfv2[t] = *(const bfrag8*)&Bs2[rofs(wn * WN + t * 16 + lm) + kk + lq * 8];
#pragma unroll
        for (int a = 0; a < TM; a++)
#pragma unroll
          for (int b = 0; b < TN; b++)
            acc[a][b] = __builtin_amdgcn_mfma_f32_16x16x32_bf16(af2[a], bfv2[b], acc[a][b], 0, 0, 0);
      }
    }
    __syncthreads();
  }

  // epilogue: C/D layout col = lane&15, row = (lane>>4)*4 + r
#pragma unroll
  for (int a = 0; a < TM; a++) {
#pragma unroll
    for (int b = 0; b < TN; b++) {
      const long mb = m0 + wm * WM + a * 16 + lq * 4;
      const long n  = n0 + wn * WN + b * 16 + lm;
      float csv = 1.f, cbv = 0.f;
      if constexpr (CS)        csv = p.cscalef[n];
      if constexpr (BIAS == 2) cbv = p.biasf[n];
      uint2 axv; axv.x = 0u; axv.y = 0u;
      if constexpr (AUXG) axv = *(const uint2*)(p.aux + n * p.ldaux + mb);
      const u16* auxp = (const u16*)&axv;
#pragma unroll
      for (int r = 0; r < 4; r++) {
        float v = acc[a][b][r] * p.scale;
        if constexpr (CS)        v *= csv;
        if constexpr (BIAS == 1) v += p.biasf[mb + r];
        if constexpr (BIAS == 2) v += cbv;
        if constexpr (AUXG) { v += bf2f(auxp[r]); v = gelu_f(v); }
        if constexpr (OUTATOMIC) unsafeAtomicAdd(&p.Cf[(mb + r) * p.ldc + n], v);
        else if constexpr (OUTF) p.Cf[(mb + r) * p.ldc + n] = v;
        else                     p.C [(mb + r) * p.ldc + n] = f2bf(v);
      }
    }
  }
}

// ---- stage kernels ----

// zero fp32 buffer (float4 stores); exact grid, no tail
__global__ void __launch_bounds__(256) k_zero(float* __restrict__ p, long n4) {
  long i = (long)blockIdx.x * 256 + threadIdx.x;
  if (i < n4) *(float4*)(p + i * 4) = make_float4(0.f, 0.f, 0.f, 0.f);
}

// fp32 -> bf16 elementwise (4 at a time)
__global__ void __launch_bounds__(256) k_cvt(const float* __restrict__ in, u16* __restrict__ out, long n4) {
  long stride = (long)gridDim.x * 256;
  for (long i = (long)blockIdx.x * 256 + threadIdx.x; i < n4; i += stride) {
    float4 f = *(const float4*)(in + i * 4);
    __bf16 e[4] = {(__bf16)f.x, (__bf16)f.y, (__bf16)f.z, (__bf16)f.w};
    uint2 r; __builtin_memcpy(&r, e, 8);
    *(uint2*)(out + i * 4) = r;
  }
}

// xhat[s,c] = sum_hw basis[hw,s] * x[c,hw]   (z: b*2+part); basis fp32, x bf16(XB)
// split-K over blockIdx.y (KSPLIT chunks), fp32 atomic accumulation into xhf.
__global__ void __launch_bounds__(256) k_fwd(const u16* __restrict__ ws_in, const float* __restrict__ bre,
                                             const float* __restrict__ bim, float* __restrict__ xhf) {
  const int z = blockIdx.z, b = z >> 1, part = z & 1;
  const long kbase = (long)blockIdx.y * (NHW / KSPLIT);
  GemmP p{};
  p.A1f = (part ? bim : bre) + (long)b * NHW * NS + kbase * NS;  // TA: elem(s,hw) at A + hw*NS + s
  p.B1  = ws_in + OFF_XB + (long)b * NC * NHW + kbase;           // elem(hw,c) at B + c*NHW + hw
  p.lda = NS; p.ldb = NHW; p.K = NHW / KSPLIT; p.scale = 1.f;
  p.Cf = xhf + (part ? (long)8 * PB : 0) + (long)b * PB; p.ldc = NC;
  gemm_core<32, 128, 64, true, false, 0, false, false, true, false, true, true>(p, blockIdx.x, 0);
}

// q/k/v complex projections: z = b*6 + proj*2 + part; weights fp32, xhat fp32
__global__ void __launch_bounds__(256) k_proj(u16* __restrict__ ws, const float* __restrict__ xhf,
                                              const float* __restrict__ awr,
                                              const float* __restrict__ awi, const float* __restrict__ abr,
                                              const float* __restrict__ abi) {
  const int z = blockIdx.z;
  const int b = z / 6, rr = z % 6, pj = rr >> 1, part = rr & 1;
  GemmP p{};
  p.A1f = xhf + (long)b * PB;                 // xhat real (fp32)
  p.A2f = xhf + (long)8 * PB + (long)b * PB;  // xhat imag (fp32)
  p.lda = NC;
  const float* Wr = awr + (long)pj * NC * NC;
  const float* Wi = awi + (long)pj * NC * NC;
  if (part == 0) { p.B1f = Wr; p.B2f = Wi; p.negB2 = 1; p.biasf = abr + pj * NC; }  // re: tr*Wr - ti*Wi
  else           { p.B1f = Wi; p.B2f = Wr; p.negB2 = 0; p.biasf = abi + pj * NC; }  // im: tr*Wi + ti*Wr
  p.ldb = NC; p.K = NC; p.scale = 1.f;
  p.C = ws + (2 + 2 * pj + part) * TOT + (long)b * PB; p.ldc = NC;
  gemm_core<32, 128, 32, false, true, 2, false, false, true, true, false, false>(p, blockIdx.x, blockIdx.y);
}

// logits[s,t] = (qr.kr + qi.ki)/sqrt(32), z = b*4+h  (all bf16)
__global__ void __launch_bounds__(256) k_logits(u16* __restrict__ ws) {
  const int z = blockIdx.z, b = z >> 2, h = z & 3;
  const long base = (long)b * PB + h * NDH;
  GemmP p{};
  p.A1 = ws + OFF_Qr + base; p.A2 = ws + OFF_Qi + base; p.lda = NC;
  p.B1 = ws + OFF_Kr + base; p.B2 = ws + OFF_Ki + base; p.ldb = NC;
  p.negB2 = 0; p.K = NDH;
  p.scale = 0.17677669529663687f;
  p.C = ws + OFF_LG + (long)z * NS * NS; p.ldc = NS;
  gemm_core<64, 64, 32, false, true, 0, false, false, false, false, false, false>(p, blockIdx.x, blockIdx.y);
}

// in-place row softmax over 576 cols, one wave per row
__global__ void __launch_bounds__(64) k_softmax(u16* __restrict__ lg) {
  u16* pr = lg + (long)blockIdx.x * NS;
  const int lane = threadIdx.x;
  float v[9];
#pragma unroll
  for (int i = 0; i < 9; i++) v[i] = bf2f(pr[lane + i * 64]);
  float mx = v[0];
#pragma unroll
  for (int i = 1; i < 9; i++) mx = fmaxf(mx, v[i]);
  for (int o = 32; o >= 1; o >>= 1) mx = fmaxf(mx, __shfl_xor(mx, o, 64));
  float s = 0.f;
#pragma unroll
  for (int i = 0; i < 9; i++) { v[i] = __expf(v[i] - mx); s += v[i]; }
  for (int o = 32; o >= 1; o >>= 1) s += __shfl_xor(s, o, 64);
  float inv = 1.f / s;
#pragma unroll
  for (int i = 0; i < 9; i++) pr[lane + i * 64] = f2bf(v[i] * inv);
}

// tiled bf16 transpose: (slab,R,C) -> (slab,C,R); R,C multiples of 32
__global__ void __launch_bounds__(256) k_transp(const u16* __restrict__ in, u16* __restrict__ out,
                                                int R, int Ccols) {
  __shared__ u16 t[32][33];
  const long slab = blockIdx.z;
  const u16* pin = in + slab * (long)R * Ccols;
  u16* pout = out + slab * (long)R * Ccols;
  const int r0 = blockIdx.x * 32, c0 = blockIdx.y * 32;
  const int j = threadIdx.x & 31, i0 = threadIdx.x >> 5;
#pragma unroll
  for (int ii = 0; ii < 4; ii++) { int i = i0 + ii * 8; t[i][j] = pin[(long)(r0 + i) * Ccols + (c0 + j)]; }
  __syncthreads();
#pragma unroll
  for (int ii = 0; ii < 4; ii++) { int i = i0 + ii * 8; pout[(long)(c0 + i) * R + (r0 + j)] = t[j][i]; }
}

// o[s,d] = sum_t P[s,t]*V^T[d,t], z = (b*4+h)*2+part (bf16)
__global__ void __launch_bounds__(256) k_attnv(u16* __restrict__ ws) {
  const int z = blockIdx.z, zz = z >> 1, part = z & 1;
  const int b = zz >> 2, h = zz & 3;
  GemmP p{};
  p.A1 = ws + OFF_LG + (long)zz * NS * NS; p.lda = NS;
  p.B1 = ws + (part ? OFF_ViT : OFF_VrT) + (long)b * NC * NS + (long)h * NDH * NS; p.ldb = NS;
  p.K = NS; p.scale = 1.f;
  p.C = ws + (part ? OFF_Oi : OFF_Or) + (long)b * PB + h * NDH; p.ldc = NC;
  gemm_core<32, 32, 64, false, false, 0, false, false, false, false, false, false>(p, blockIdx.x, blockIdx.y);
}

// o-projection (index 3), z = b*2+part; weights fp32
__global__ void __launch_bounds__(256) k_oproj(u16* __restrict__ ws, const float* __restrict__ awr,
                                               const float* __restrict__ awi, const float* __restrict__ abr,
                                               const float* __restrict__ abi) {
  const int z = blockIdx.z, b = z >> 1, part = z & 1;
  GemmP p{};
  p.A1 = ws + OFF_Or + (long)b * PB; p.A2 = ws + OFF_Oi + (long)b * PB; p.lda = NC;
  const float* Wr = awr + 3l * NC * NC;
  const float* Wi = awi + 3l * NC * NC;
  if (part == 0) { p.B1f = Wr; p.B2f = Wi; p.negB2 = 1; p.biasf = abr + 3 * NC; }
  else           { p.B1f = Wi; p.B2f = Wr; p.negB2 = 0; p.biasf = abi + 3 * NC; }
  p.ldb = NC; p.K = NC; p.scale = 1.f;
  p.C = ws + (part ? OFF_OHi : OFF_OHr) + (long)b * PB; p.ldc = NC;
  gemm_core<32, 128, 32, false, true, 2, false, false, false, true, false, false>(p, blockIdx.x, blockIdx.y);
}

// x_rec[hw,c] = (sum_s ohr[s,c]*br[hw,s] + ohi[s,c]*bi[hw,s]) * alpha[c], z = b; basis fp32
__global__ void __launch_bounds__(256) k_inv(u16* __restrict__ ws, const float* __restrict__ bre,
                                             const float* __restrict__ bim, const float* __restrict__ alpha) {
  const int b = blockIdx.z;
  GemmP p{};
  p.A1f = bre + (long)b * NHW * NS; p.A2f = bim + (long)b * NHW * NS; p.lda = NS;
  p.B1 = ws + OFF_OHrT + (long)b * NC * NS; p.B2 = ws + OFF_OHiT + (long)b * NC * NS; p.ldb = NS;
  p.negB2 = 0; p.K = NS; p.scale = 1.f;
  p.cscalef = alpha;
  p.C = ws + OFF_XR + (long)b * NHW * NC; p.ldc = NC;
  gemm_core<64, 128, 32, false, true, 0, true, false, true, false, false, false>(p, blockIdx.x, blockIdx.y);
}

// mixer: y[hw,co] = sum_c xr[hw,c]*W[co,c] + mb[co]  (in-place over XR, z = b); W fp32
// safe in place: each block reads exactly the A rows it writes (n covers full NC).
__global__ void __launch_bounds__(256) k_mixer(u16* __restrict__ ws, const float* __restrict__ mw,
                                               const float* __restrict__ mb) {
  const int b = blockIdx.z;
  GemmP p{};
  p.A1 = ws + OFF_XR + (long)b * NHW * NC; p.lda = NC;
  p.B1f = mw; p.ldb = NC;
  p.K = NC; p.scale = 1.f; p.biasf = mb;
  p.C = ws + OFF_XR + (long)b * NHW * NC; p.ldc = NC;
  gemm_core<64, 128, 32, false, false, 2, false, false, false, true, false, false>(p, blockIdx.x, blockIdx.y);
}

// layernorm(c) + gelu, in place; one wave per 128-col row, 4 rows/block
__global__ void __launch_bounds__(256) k_ln(u16* __restrict__ y, const float* __restrict__ g,
                                            const float* __restrict__ be) {
  const long row = (long)blockIdx.x * 4 + (threadIdx.x >> 6);
  const int lane = threadIdx.x & 63;
  u16* pr = y + row * NC;
  float a = bf2f(pr[lane]), b = bf2f(pr[lane + 64]);
  float s = a + b;
  for (int o = 32; o >= 1; o >>= 1) s += __shfl_xor(s, o, 64);
  float mu = s * (1.f / 128.f);
  float da = a - mu, db = b - mu;
  float q = da * da + db * db;
  for (int o = 32; o >= 1; o >>= 1) q += __shfl_xor(q, o, 64);
  float r = rsqrtf(q * (1.f / 128.f) + 1e-5f);
  float o1 = da * r * g[lane] + be[lane];
  float o2 = db * r * g[lane + 64] + be[lane + 64];
  pr[lane] = f2bf(gelu_f(o1));
  pr[lane + 64] = f2bf(gelu_f(o2));
}

// out[co,hw] = gelu( y[hw,co] + sum_c sw[co,c]*xT[hw,c] + sb[co] ), z = b; sw fp32, out fp32
__global__ void __launch_bounds__(256) k_final(const u16* __restrict__ ws, const float* __restrict__ sw,
                                               const float* __restrict__ sb, float* __restrict__ out) {
  const int b = blockIdx.z;
  GemmP p{};
  p.A1f = sw; p.lda = NC;
  p.B1 = ws + OFF_XT + (long)b * NHW * NC; p.ldb = NC;
  p.K = NC; p.scale = 1.f;
  p.biasf = sb;                                            // row bias (per co)
  p.aux = ws + OFF_XR + (long)b * NHW * NC; p.ldaux = NC;  // y[hw,co] read transposed (bf16)
  p.Cf = out + (long)b * NC * NHW; p.ldc = NHW;
  gemm_core<128, 64, 32, false, false, 1, false, true, true, false, true, false>(p, blockIdx.x, blockIdx.y);
}

extern "C" void kernel_launch(void* const* d_in, const int* in_sizes, int n_in,
                              void* d_out, int out_size, void* d_ws, size_t ws_size,
                              hipStream_t stream) {
  (void)in_sizes; (void)n_in; (void)out_size; (void)ws_size;
  const float* x    = (const float*)d_in[0];
  const float* bre  = (const float*)d_in[1];
  const float* bim  = (const float*)d_in[2];
  const float* awr  = (const float*)d_in[3];
  const float* awi  = (const float*)d_in[4];
  const float* abr  = (const float*)d_in[5];
  const float* abi  = (const float*)d_in[6];
  const float* alp  = (const float*)d_in[7];
  const float* mw   = (const float*)d_in[8];
  const float* mbp  = (const float*)d_in[9];
  const float* ng   = (const float*)d_in[10];
  const float* nbta = (const float*)d_in[11];
  const float* sw   = (const float*)d_in[12];
  const float* sb   = (const float*)d_in[13];
  u16*   ws  = (u16*)d_ws;
  float* xhf = (float*)(ws + OFF_LG);   // fp32 xhat accumulator (16*PB floats)
  float* out = (float*)d_out;
  const dim3 T256(256);

  k_zero   <<<dim3(1152),      T256,    0, stream>>>(xhf, (long)16 * PB / 4);
  k_cvt    <<<dim3(1024),      T256,    0, stream>>>(x, ws + OFF_XB, (long)8 * NC * NHW / 4);
  k_fwd    <<<dim3(18, KSPLIT, 16), T256, 0, stream>>>(ws, bre, bim, xhf);
  k_proj   <<<dim3(18, 1, 48), T256,    0, stream>>>(ws, xhf, awr, awi, abr, abi);
  k_logits <<<dim3(9, 9, 32),  T256,    0, stream>>>(ws);
  k_softmax<<<dim3(32 * NS),   dim3(64),0, stream>>>(ws + OFF_LG);
  k_transp <<<dim3(18, 4, 16), T256,    0, stream>>>(ws + OFF_Vr, ws + OFF_VrT, NS, NC);
  k_attnv  <<<dim3(18, 1, 64), T256,    0, stream>>>(ws);
  k_transp <<<dim3(4, 288, 8), T256,    0, stream>>>(ws + OFF_XB, ws + OFF_XT, NC, NHW);  // after attnv: LG dead
  k_oproj  <<<dim3(18, 1, 16), T256,    0, stream>>>(ws, awr, awi, abr, abi);
  k_transp <<<dim3(18, 4, 16), T256,    0, stream>>>(ws + OFF_OHr, ws + OFF_OHrT, NS, NC);
  k_inv    <<<dim3(144, 1, 8), T256,    0, stream>>>(ws, bre, bim, alp);
  k_mixer  <<<dim3(144, 1, 8), T256,    0, stream>>>(ws, mw, mbp);
  k_ln     <<<dim3(18432),     T256,    0, stream>>>(ws + OFF_XR, ng, nbta);
  k_final  <<<dim3(1, 144, 8), T256,    0, stream>>>(ws, sw, sb, out);
}

// Round 6
// 636.354 us; speedup vs baseline: 1.4285x; 1.0408x over previous
//
#include <hip/hip_runtime.h>
#include <hip/hip_bf16.h>

typedef unsigned short u16;
typedef unsigned int   u32;
typedef __bf16 bfrag8 __attribute__((ext_vector_type(8)));
typedef float  ffrag4 __attribute__((ext_vector_type(4)));

#define DEVI __device__ __forceinline__

// ---- problem constants ----
constexpr int  NC  = 128;
constexpr int  NHW = 96 * 96;   // 9216
constexpr int  NS  = 576;       // 24*24 tokens
constexpr int  NDH = 32;        // head dim
constexpr int  KSPLIT = 16;     // k_fwd split-K factor (9216/16 = 576, mult of 32)

constexpr long PB  = (long)NS * NC;   // 73728
constexpr long TOT = (long)8 * PB;    // 589824

// ---- workspace layout (u16 element offsets), bf16 intermediates ----
constexpr long OFF_XHr  = 0 * TOT;   // (dead — kept for layout stability)
constexpr long OFF_XHi  = 1 * TOT;
constexpr long OFF_Qr   = 2 * TOT;
constexpr long OFF_Qi   = 3 * TOT;
constexpr long OFF_Kr   = 4 * TOT;
constexpr long OFF_Ki   = 5 * TOT;
constexpr long OFF_Vr   = 6 * TOT;
constexpr long OFF_Vi   = 7 * TOT;
constexpr long OFF_VrT  = 8 * TOT;
constexpr long OFF_ViT  = 9 * TOT;
constexpr long OFF_Or   = 10 * TOT;
constexpr long OFF_Oi   = 11 * TOT;
constexpr long OFF_OHr  = 12 * TOT;
constexpr long OFF_OHi  = 13 * TOT;
constexpr long OFF_OHrT = 14 * TOT;
constexpr long OFF_OHiT = 15 * TOT;
constexpr long OFF_LG   = 16 * TOT;  // logits/probs: 32*576*576 = 18*TOT
// fp32 xhat accumulator (re then im, 16*PB floats = 4.7 MB) lives at the FRONT
// of the LG region: written by k_fwd (atomics), read by k_proj, then k_logits
// overwrites the region. XT reuses LG after attnv as before.
constexpr long OFF_XT   = 16 * TOT;  // x^T bf16 (hw,c) — reuses LG AFTER attnv
constexpr long OFF_XB   = 34 * TOT;  // x bf16 (b,c,hw) — lives here until k_inv
constexpr long OFF_XR   = 34 * TOT;  // x_rec / mixer / ln (b,hw,c) — written by k_inv
// total: 50*TOT*2 bytes ~= 59 MB

DEVI float bf2f(u16 x) { u32 u = ((u32)x) << 16; float f; __builtin_memcpy(&f, &u, 4); return f; }
DEVI u16   f2bf(float f) { u32 u; __builtin_memcpy(&u, &f, 4); u += 0x7fffu + ((u >> 16) & 1u); return (u16)(u >> 16); }
DEVI float gelu_f(float x) {   // JAX default gelu: tanh approximation
  float y = 0.7978845608028654f * (x + 0.044715f * x * x * x);
  float t = 1.0f - 2.0f / (__expf(2.0f * y) + 1.0f);  // stable tanh(y)
  return 0.5f * x * (1.0f + t);
}

DEVI uint4 ldg4(const void* p) { return *(const uint4*)p; }
// pack 8 raw-fp32 (two uint4) to 8 bf16 (one uint4), native RNE cvt
DEVI uint4 pack8(uint4 lo, uint4 hi) {
  float f[8];
  __builtin_memcpy(f, &lo, 16); __builtin_memcpy(f + 4, &hi, 16);
  __bf16 e[8] = {(__bf16)f[0], (__bf16)f[1], (__bf16)f[2], (__bf16)f[3],
                 (__bf16)f[4], (__bf16)f[5], (__bf16)f[6], (__bf16)f[7]};
  uint4 r; __builtin_memcpy(&r, e, 16); return r;
}

struct GemmP {
  const u16*   A1; const u16*   A2;    // bf16 sources
  const u16*   B1; const u16*   B2;
  const float* A1f; const float* A2f;  // fp32 sources (used when AF32/BF32)
  const float* B1f; const float* B2f;
  int lda, ldb, K, negB2;
  u16* C; float* Cf; int ldc;
  float scale;
  const float* biasf;    // BIAS==1: per-row[m], BIAS==2: per-col[n]
  const float* cscalef;  // per-col scale (alpha)
  const u16*   aux;      // aux add (bf16, read at aux[n*ldaux+m]) then gelu
  int ldaux;
};

// C[m,n] = scale*(A1·B1 (+/-) A2·B2) [+bias][*cscale][+aux->gelu], fp32 acc.
// A "easy": elem(m,k) at A + m*lda + k (k contig). TA: elem(m,k) at A + k*lda + m.
// B always: elem(k,n) at B + n*ldb + k (k contig).
// BKT: K-chunk per LDS stage (multiple of 32; p.K must be a multiple of BKT).
// Register prefetch (T14, safe variant): tile t+1's global loads are issued
// between the produce-sync and compute(t), so HBM latency hides under compute;
// the consume-sync's vmcnt drain lands after compute. Both barriers are plain
// __syncthreads() (full fence) — no raw-barrier race (round-5 lesson).
// LDS swizzle lat(r,k): row pad +8 u16, row-group offset ((r>>3)&1)*8
// (injective: drop at wrap == pad), and col-group XOR ((r>>4)&3) — bijective
// within row, spreads TA scalar stores across bank groups; reads use the same
// key (constant within any 16-aligned fragment, so b128 reads stay aligned).
template <int BM, int BN, int BKT, bool TA, bool DUAL, int BIAS, bool CS, bool AUXG,
          bool AF32, bool BF32, bool OUTF, bool OUTATOMIC>
DEVI void gemm_core(const GemmP p, int bx, int by) {
  constexpr int BKPt = BKT + 8;
  __shared__ u16 As1[BM * BKPt + 32];
  __shared__ u16 Bs1[BN * BKPt + 32];
  __shared__ u16 As2[DUAL ? BM * BKPt + 32 : 8];
  __shared__ u16 Bs2[DUAL ? BN * BKPt + 32 : 8];

  const int tid  = threadIdx.x;
  const int lane = tid & 63;
  const int wave = tid >> 6;
  const int wm = wave >> 1, wn = wave & 1;
  constexpr int WM = BM / 2, WN = BN / 2, TM = WM / 16, TN = WN / 16;
  const int lm = lane & 15, lq = lane >> 4;
  const long m0 = (long)bx * BM;
  const long n0 = (long)by * BN;

  constexpr int KV = BKT / 8;
  constexpr int MV = BM / 8;
  constexpr int AITEMS = TA ? MV * BKT : BM * KV;
  constexpr int AI = (AITEMS + 255) / 256;
  constexpr int BITEMS = BN * KV;
  constexpr int BI = (BITEMS + 255) / 256;

  auto lat = [](int r, int k) {
    int g = (((k >> 3) ^ ((r >> 4) & 3)) << 3) | (k & 7);
    return r * BKPt + ((r >> 3) & 1) * 8 + g;
  };

  // raw staging registers (bits; fp32 kept raw, converted at store time)
  uint4 ra1[AI], ra1h[AI], ra2[AI], ra2h[AI];
  uint4 rb1[BI], rb1h[BI], rb2[BI], rb2h[BI];

  auto stage_load = [&](int k0) {
#pragma unroll
    for (int j = 0; j < AI; j++) {
      int i = tid + j * 256;
      if (AITEMS % 256 == 0 || i < AITEMS) {
        long off;
        if constexpr (TA) { int k = i / MV, mv = (i % MV) * 8; off = (long)(k0 + k) * p.lda + m0 + mv; }
        else              { int m = i / KV, kv = (i % KV) * 8; off = (m0 + (long)m) * p.lda + k0 + kv; }
        if constexpr (AF32) {
          ra1[j] = ldg4(p.A1f + off); ra1h[j] = ldg4(p.A1f + off + 4);
          if constexpr (DUAL) { ra2[j] = ldg4(p.A2f + off); ra2h[j] = ldg4(p.A2f + off + 4); }
        } else {
          ra1[j] = ldg4(p.A1 + off);
          if constexpr (DUAL) ra2[j] = ldg4(p.A2 + off);
        }
      }
    }
#pragma unroll
    for (int j = 0; j < BI; j++) {
      int i = tid + j * 256;
      if (BITEMS % 256 == 0 || i < BITEMS) {
        int n = i / KV, kv = (i % KV) * 8;
        long off = (n0 + (long)n) * p.ldb + k0 + kv;
        if constexpr (BF32) {
          rb1[j] = ldg4(p.B1f + off); rb1h[j] = ldg4(p.B1f + off + 4);
          if constexpr (DUAL) { rb2[j] = ldg4(p.B2f + off); rb2h[j] = ldg4(p.B2f + off + 4); }
        } else {
          rb1[j] = ldg4(p.B1 + off);
          if constexpr (DUAL) rb2[j] = ldg4(p.B2 + off);
        }
      }
    }
  };

  auto stage_store = [&]() {
#pragma unroll
    for (int j = 0; j < AI; j++) {
      int i = tid + j * 256;
      if (AITEMS % 256 == 0 || i < AITEMS) {
        uint4 v1 = AF32 ? pack8(ra1[j], ra1h[j]) : ra1[j];
        uint4 v2;
        if constexpr (DUAL) v2 = AF32 ? pack8(ra2[j], ra2h[j]) : ra2[j];
        if constexpr (TA) {
          int k = i / MV, mv = (i % MV) * 8;
          u16 e[8]; __builtin_memcpy(e, &v1, 16);
#pragma unroll
          for (int jj = 0; jj < 8; jj++) As1[lat(mv + jj, k)] = e[jj];
          if constexpr (DUAL) {
            u16 e2[8]; __builtin_memcpy(e2, &v2, 16);
#pragma unroll
            for (int jj = 0; jj < 8; jj++) As2[lat(mv + jj, k)] = e2[jj];
          }
        } else {
          int m = i / KV, kv = (i % KV) * 8;
          *(uint4*)&As1[lat(m, kv)] = v1;
          if constexpr (DUAL) *(uint4*)&As2[lat(m, kv)] = v2;
        }
      }
    }
#pragma unroll
    for (int j = 0; j < BI; j++) {
      int i = tid + j * 256;
      if (BITEMS % 256 == 0 || i < BITEMS) {
        int n = i / KV, kv = (i % KV) * 8;
        uint4 v1 = BF32 ? pack8(rb1[j], rb1h[j]) : rb1[j];
        *(uint4*)&Bs1[lat(n, kv)] = v1;
        if constexpr (DUAL) {
          uint4 v2 = BF32 ? pack8(rb2[j], rb2h[j]) : rb2[j];
          if (p.negB2) { v2.x ^= 0x80008000u; v2.y ^= 0x80008000u; v2.z ^= 0x80008000u; v2.w ^= 0x80008000u; }
          *(uint4*)&Bs2[lat(n, kv)] = v2;
        }
      }
    }
  };

  ffrag4 acc[TM][TN];
  const ffrag4 z4 = {0.f, 0.f, 0.f, 0.f};
#pragma unroll
  for (int a = 0; a < TM; a++)
#pragma unroll
    for (int b = 0; b < TN; b++) acc[a][b] = z4;

  stage_load(0);
  const int nt = p.K / BKT;
  for (int t = 0; t < nt; t++) {
    stage_store();          // waits tile-t loads (compiler vmcnt), writes LDS
    __syncthreads();        // produce barrier (full fence; no extra drain)
    if (t + 1 < nt) stage_load((t + 1) * BKT);  // overlap with compute below
#pragma unroll
    for (int kk = 0; kk < BKT; kk += 32) {
      bfrag8 af[TM], bfv[TN];
#pragma unroll
      for (int t2 = 0; t2 < TM; t2++) af[t2] = *(const bfrag8*)&As1[lat(wm * WM + t2 * 16 + lm, kk + lq * 8)];
#pragma unroll
      for (int t2 = 0; t2 < TN; t2++) bfv[t2] = *(const bfrag8*)&Bs1[lat(wn * WN + t2 * 16 + lm, kk + lq * 8)];
#pragma unroll
      for (int a = 0; a < TM; a++)
#pragma unroll
        for (int b = 0; b < TN; b++)
          acc[a][b] = __builtin_amdgcn_mfma_f32_16x16x32_bf16(af[a], bfv[b], acc[a][b], 0, 0, 0);
      if constexpr (DUAL) {
        bfrag8 af2[TM], bfv2[TN];
#pragma unroll
        for (int t2 = 0; t2 < TM; t2++) af2[t2] = *(const bfrag8*)&As2[lat(wm * WM + t2 * 16 + lm, kk + lq * 8)];
#pragma unroll
        for (int t2 = 0; t2 < TN; t2++) bfv2[t2] = *(const bfrag8*)&Bs2[lat(wn * WN + t2 * 16 + lm, kk + lq * 8)];
#pragma unroll
        for (int a = 0; a < TM; a++)
#pragma unroll
          for (int b = 0; b < TN; b++)
            acc[a][b] = __builtin_amdgcn_mfma_f32_16x16x32_bf16(af2[a], bfv2[b], acc[a][b], 0, 0, 0);
      }
    }
    __syncthreads();        // consume barrier (drains t+1 loads AFTER compute)
  }

  // epilogue: C/D layout col = lane&15, row = (lane>>4)*4 + r
#pragma unroll
  for (int a = 0; a < TM; a++) {
#pragma unroll
    for (int b = 0; b < TN; b++) {
      const long mb = m0 + wm * WM + a * 16 + lq * 4;
      const long n  = n0 + wn * WN + b * 16 + lm;
      float csv = 1.f, cbv = 0.f;
      if constexpr (CS)        csv = p.cscalef[n];
      if constexpr (BIAS == 2) cbv = p.biasf[n];
      uint2 axv; axv.x = 0u; axv.y = 0u;
      if constexpr (AUXG) axv = *(const uint2*)(p.aux + n * p.ldaux + mb);
      const u16* auxp = (const u16*)&axv;
#pragma unroll
      for (int r = 0; r < 4; r++) {
        float v = acc[a][b][r] * p.scale;
        if constexpr (CS)        v *= csv;
        if constexpr (BIAS == 1) v += p.biasf[mb + r];
        if constexpr (BIAS == 2) v += cbv;
        if constexpr (AUXG) { v += bf2f(auxp[r]); v = gelu_f(v); }
        if constexpr (OUTATOMIC) unsafeAtomicAdd(&p.Cf[(mb + r) * p.ldc + n], v);
        else if constexpr (OUTF) p.Cf[(mb + r) * p.ldc + n] = v;
        else                     p.C [(mb + r) * p.ldc + n] = f2bf(v);
      }
    }
  }
}

// ---- stage kernels ----

// zero fp32 buffer (float4 stores); exact grid, no tail
__global__ void __launch_bounds__(256) k_zero(float* __restrict__ p, long n4) {
  long i = (long)blockIdx.x * 256 + threadIdx.x;
  if (i < n4) *(float4*)(p + i * 4) = make_float4(0.f, 0.f, 0.f, 0.f);
}

// fp32 -> bf16 elementwise (4 at a time)
__global__ void __launch_bounds__(256) k_cvt(const float* __restrict__ in, u16* __restrict__ out, long n4) {
  long stride = (long)gridDim.x * 256;
  for (long i = (long)blockIdx.x * 256 + threadIdx.x; i < n4; i += stride) {
    float4 f = *(const float4*)(in + i * 4);
    __bf16 e[4] = {(__bf16)f.x, (__bf16)f.y, (__bf16)f.z, (__bf16)f.w};
    uint2 r; __builtin_memcpy(&r, e, 8);
    *(uint2*)(out + i * 4) = r;
  }
}

// xhat[s,c] = sum_hw basis[hw,s] * x[c,hw]   (z: b*2+part); basis fp32, x bf16(XB)
// split-K over blockIdx.y (KSPLIT chunks), fp32 atomic accumulation into xhf.
__global__ void __launch_bounds__(256) k_fwd(const u16* __restrict__ ws_in, const float* __restrict__ bre,
                                             const float* __restrict__ bim, float* __restrict__ xhf) {
  const int z = blockIdx.z, b = z >> 1, part = z & 1;
  const long kbase = (long)blockIdx.y * (NHW / KSPLIT);
  GemmP p{};
  p.A1f = (part ? bim : bre) + (long)b * NHW * NS + kbase * NS;  // TA: elem(s,hw) at A + hw*NS + s
  p.B1  = ws_in + OFF_XB + (long)b * NC * NHW + kbase;           // elem(hw,c) at B + c*NHW + hw
  p.lda = NS; p.ldb = NHW; p.K = NHW / KSPLIT; p.scale = 1.f;
  p.Cf = xhf + (part ? (long)8 * PB : 0) + (long)b * PB; p.ldc = NC;
  gemm_core<64, 128, 32, true, false, 0, false, false, true, false, true, true>(p, blockIdx.x, 0);
}

// q/k/v complex projections: z = b*6 + proj*2 + part; weights fp32, xhat fp32
__global__ void __launch_bounds__(256) k_proj(u16* __restrict__ ws, const float* __restrict__ xhf,
                                              const float* __restrict__ awr,
                                              const float* __restrict__ awi, const float* __restrict__ abr,
                                              const float* __restrict__ abi) {
  const int z = blockIdx.z;
  const int b = z / 6, rr = z % 6, pj = rr >> 1, part = rr & 1;
  GemmP p{};
  p.A1f = xhf + (long)b * PB;                 // xhat real (fp32)
  p.A2f = xhf + (long)8 * PB + (long)b * PB;  // xhat imag (fp32)
  p.lda = NC;
  const float* Wr = awr + (long)pj * NC * NC;
  const float* Wi = awi + (long)pj * NC * NC;
  if (part == 0) { p.B1f = Wr; p.B2f = Wi; p.negB2 = 1; p.biasf = abr + pj * NC; }  // re: tr*Wr - ti*Wi
  else           { p.B1f = Wi; p.B2f = Wr; p.negB2 = 0; p.biasf = abi + pj * NC; }  // im: tr*Wi + ti*Wr
  p.ldb = NC; p.K = NC; p.scale = 1.f;
  p.C = ws + (2 + 2 * pj + part) * TOT + (long)b * PB; p.ldc = NC;
  gemm_core<32, 128, 32, false, true, 2, false, false, true, true, false, false>(p, blockIdx.x, blockIdx.y);
}

// logits[s,t] = (qr.kr + qi.ki)/sqrt(32), z = b*4+h  (all bf16)
__global__ void __launch_bounds__(256) k_logits(u16* __restrict__ ws) {
  const int z = blockIdx.z, b = z >> 2, h = z & 3;
  const long base = (long)b * PB + h * NDH;
  GemmP p{};
  p.A1 = ws + OFF_Qr + base; p.A2 = ws + OFF_Qi + base; p.lda = NC;
  p.B1 = ws + OFF_Kr + base; p.B2 = ws + OFF_Ki + base; p.ldb = NC;
  p.negB2 = 0; p.K = NDH;
  p.scale = 0.17677669529663687f;
  p.C = ws + OFF_LG + (long)z * NS * NS; p.ldc = NS;
  gemm_core<64, 64, 32, false, true, 0, false, false, false, false, false, false>(p, blockIdx.x, blockIdx.y);
}

// in-place row softmax over 576 cols, one wave per row
__global__ void __launch_bounds__(64) k_softmax(u16* __restrict__ lg) {
  u16* pr = lg + (long)blockIdx.x * NS;
  const int lane = threadIdx.x;
  float v[9];
#pragma unroll
  for (int i = 0; i < 9; i++) v[i] = bf2f(pr[lane + i * 64]);
  float mx = v[0];
#pragma unroll
  for (int i = 1; i < 9; i++) mx = fmaxf(mx, v[i]);
  for (int o = 32; o >= 1; o >>= 1) mx = fmaxf(mx, __shfl_xor(mx, o, 64));
  float s = 0.f;
#pragma unroll
  for (int i = 0; i < 9; i++) { v[i] = __expf(v[i] - mx); s += v[i]; }
  for (int o = 32; o >= 1; o >>= 1) s += __shfl_xor(s, o, 64);
  float inv = 1.f / s;
#pragma unroll
  for (int i = 0; i < 9; i++) pr[lane + i * 64] = f2bf(v[i] * inv);
}

// tiled bf16 transpose: (slab,R,C) -> (slab,C,R); R,C multiples of 32
__global__ void __launch_bounds__(256) k_transp(const u16* __restrict__ in, u16* __restrict__ out,
                                                int R, int Ccols) {
  __shared__ u16 t[32][33];
  const long slab = blockIdx.z;
  const u16* pin = in + slab * (long)R * Ccols;
  u16* pout = out + slab * (long)R * Ccols;
  const int r0 = blockIdx.x * 32, c0 = blockIdx.y * 32;
  const int j = threadIdx.x & 31, i0 = threadIdx.x >> 5;
#pragma unroll
  for (int ii = 0; ii < 4; ii++) { int i = i0 + ii * 8; t[i][j] = pin[(long)(r0 + i) * Ccols + (c0 + j)]; }
  __syncthreads();
#pragma unroll
  for (int ii = 0; ii < 4; ii++) { int i = i0 + ii * 8; pout[(long)(c0 + i) * R + (r0 + j)] = t[j][i]; }
}

// o[s,d] = sum_t P[s,t]*V^T[d,t], z = (b*4+h)*2+part (bf16)
__global__ void __launch_bounds__(256) k_attnv(u16* __restrict__ ws) {
  const int z = blockIdx.z, zz = z >> 1, part = z & 1;
  const int b = zz >> 2, h = zz & 3;
  GemmP p{};
  p.A1 = ws + OFF_LG + (long)zz * NS * NS; p.lda = NS;
  p.B1 = ws + (part ? OFF_ViT : OFF_VrT) + (long)b * NC * NS + (long)h * NDH * NS; p.ldb = NS;
  p.K = NS; p.scale = 1.f;
  p.C = ws + (part ? OFF_Oi : OFF_Or) + (long)b * PB + h * NDH; p.ldc = NC;
  gemm_core<32, 32, 64, false, false, 0, false, false, false, false, false, false>(p, blockIdx.x, blockIdx.y);
}

// o-projection (index 3), z = b*2+part; weights fp32
__global__ void __launch_bounds__(256) k_oproj(u16* __restrict__ ws, const float* __restrict__ awr,
                                               const float* __restrict__ awi, const float* __restrict__ abr,
                                               const float* __restrict__ abi) {
  const int z = blockIdx.z, b = z >> 1, part = z & 1;
  GemmP p{};
  p.A1 = ws + OFF_Or + (long)b * PB; p.A2 = ws + OFF_Oi + (long)b * PB; p.lda = NC;
  const float* Wr = awr + 3l * NC * NC;
  const float* Wi = awi + 3l * NC * NC;
  if (part == 0) { p.B1f = Wr; p.B2f = Wi; p.negB2 = 1; p.biasf = abr + 3 * NC; }
  else           { p.B1f = Wi; p.B2f = Wr; p.negB2 = 0; p.biasf = abi + 3 * NC; }
  p.ldb = NC; p.K = NC; p.scale = 1.f;
  p.C = ws + (part ? OFF_OHi : OFF_OHr) + (long)b * PB; p.ldc = NC;
  gemm_core<32, 128, 32, false, true, 2, false, false, false, true, false, false>(p, blockIdx.x, blockIdx.y);
}

// x_rec[hw,c] = (sum_s ohr[s,c]*br[hw,s] + ohi[s,c]*bi[hw,s]) * alpha[c], z = b; basis fp32
__global__ void __launch_bounds__(256) k_inv(u16* __restrict__ ws, const float* __restrict__ bre,
                                             const float* __restrict__ bim, const float* __restrict__ alpha) {
  const int b = blockIdx.z;
  GemmP p{};
  p.A1f = bre + (long)b * NHW * NS; p.A2f = bim + (long)b * NHW * NS; p.lda = NS;
  p.B1 = ws + OFF_OHrT + (long)b * NC * NS; p.B2 = ws + OFF_OHiT + (long)b * NC * NS; p.ldb = NS;
  p.negB2 = 0; p.K = NS; p.scale = 1.f;
  p.cscalef = alpha;
  p.C = ws + OFF_XR + (long)b * NHW * NC; p.ldc = NC;
  gemm_core<64, 128, 32, false, true, 0, true, false, true, false, false, false>(p, blockIdx.x, blockIdx.y);
}

// mixer: y[hw,co] = sum_c xr[hw,c]*W[co,c] + mb[co]  (in-place over XR, z = b); W fp32
// safe in place: each block reads exactly the A rows it writes (n covers full NC).
__global__ void __launch_bounds__(256) k_mixer(u16* __restrict__ ws, const float* __restrict__ mw,
                                               const float* __restrict__ mb) {
  const int b = blockIdx.z;
  GemmP p{};
  p.A1 = ws + OFF_XR + (long)b * NHW * NC; p.lda = NC;
  p.B1f = mw; p.ldb = NC;
  p.K = NC; p.scale = 1.f; p.biasf = mb;
  p.C = ws + OFF_XR + (long)b * NHW * NC; p.ldc = NC;
  gemm_core<64, 128, 32, false, false, 2, false, false, false, true, false, false>(p, blockIdx.x, blockIdx.y);
}

// layernorm(c) + gelu, in place; one wave per 128-col row, 4 rows/block
__global__ void __launch_bounds__(256) k_ln(u16* __restrict__ y, const float* __restrict__ g,
                                            const float* __restrict__ be) {
  const long row = (long)blockIdx.x * 4 + (threadIdx.x >> 6);
  const int lane = threadIdx.x & 63;
  u16* pr = y + row * NC;
  float a = bf2f(pr[lane]), b = bf2f(pr[lane + 64]);
  float s = a + b;
  for (int o = 32; o >= 1; o >>= 1) s += __shfl_xor(s, o, 64);
  float mu = s * (1.f / 128.f);
  float da = a - mu, db = b - mu;
  float q = da * da + db * db;
  for (int o = 32; o >= 1; o >>= 1) q += __shfl_xor(q, o, 64);
  float r = rsqrtf(q * (1.f / 128.f) + 1e-5f);
  float o1 = da * r * g[lane] + be[lane];
  float o2 = db * r * g[lane + 64] + be[lane + 64];
  pr[lane] = f2bf(gelu_f(o1));
  pr[lane + 64] = f2bf(gelu_f(o2));
}

// out[co,hw] = gelu( y[hw,co] + sum_c sw[co,c]*xT[hw,c] + sb[co] ), z = b; sw fp32, out fp32
__global__ void __launch_bounds__(256) k_final(const u16* __restrict__ ws, const float* __restrict__ sw,
                                               const float* __restrict__ sb, float* __restrict__ out) {
  const int b = blockIdx.z;
  GemmP p{};
  p.A1f = sw; p.lda = NC;
  p.B1 = ws + OFF_XT + (long)b * NHW * NC; p.ldb = NC;
  p.K = NC; p.scale = 1.f;
  p.biasf = sb;                                            // row bias (per co)
  p.aux = ws + OFF_XR + (long)b * NHW * NC; p.ldaux = NC;  // y[hw,co] read transposed (bf16)
  p.Cf = out + (long)b * NC * NHW; p.ldc = NHW;
  gemm_core<128, 64, 32, false, false, 1, false, true, true, false, true, false>(p, blockIdx.x, blockIdx.y);
}

extern "C" void kernel_launch(void* const* d_in, const int* in_sizes, int n_in,
                              void* d_out, int out_size, void* d_ws, size_t ws_size,
                              hipStream_t stream) {
  (void)in_sizes; (void)n_in; (void)out_size; (void)ws_size;
  const float* x    = (const float*)d_in[0];
  const float* bre  = (const float*)d_in[1];
  const float* bim  = (const float*)d_in[2];
  const float* awr  = (const float*)d_in[3];
  const float* awi  = (const float*)d_in[4];
  const float* abr  = (const float*)d_in[5];
  const float* abi  = (const float*)d_in[6];
  const float* alp  = (const float*)d_in[7];
  const float* mw   = (const float*)d_in[8];
  const float* mbp  = (const float*)d_in[9];
  const float* ng   = (const float*)d_in[10];
  const float* nbta = (const float*)d_in[11];
  const float* sw   = (const float*)d_in[12];
  const float* sb   = (const float*)d_in[13];
  u16*   ws  = (u16*)d_ws;
  float* xhf = (float*)(ws + OFF_LG);   // fp32 xhat accumulator (16*PB floats)
  float* out = (float*)d_out;
  const dim3 T256(256);

  k_zero   <<<dim3(1152),      T256,    0, stream>>>(xhf, (long)16 * PB / 4);
  k_cvt    <<<dim3(1024),      T256,    0, stream>>>(x, ws + OFF_XB, (long)8 * NC * NHW / 4);
  k_fwd    <<<dim3(9, KSPLIT, 16), T256, 0, stream>>>(ws, bre, bim, xhf);
  k_proj   <<<dim3(18, 1, 48), T256,    0, stream>>>(ws, xhf, awr, awi, abr, abi);
  k_logits <<<dim3(9, 9, 32),  T256,    0, stream>>>(ws);
  k_softmax<<<dim3(32 * NS),   dim3(64),0, stream>>>(ws + OFF_LG);
  k_transp <<<dim3(18, 4, 16), T256,    0, stream>>>(ws + OFF_Vr, ws + OFF_VrT, NS, NC);
  k_attnv  <<<dim3(18, 1, 64), T256,    0, stream>>>(ws);
  k_transp <<<dim3(4, 288, 8), T256,    0, stream>>>(ws + OFF_XB, ws + OFF_XT, NC, NHW);  // after attnv: LG dead
  k_oproj  <<<dim3(18, 1, 16), T256,    0, stream>>>(ws, awr, awi, abr, abi);
  k_transp <<<dim3(18, 4, 16), T256,    0, stream>>>(ws + OFF_OHr, ws + OFF_OHrT, NS, NC);
  k_inv    <<<dim3(144, 1, 8), T256,    0, stream>>>(ws, bre, bim, alp);
  k_mixer  <<<dim3(144, 1, 8), T256,    0, stream>>>(ws, mw, mbp);
  k_ln     <<<dim3(18432),     T256,    0, stream>>>(ws + OFF_XR, ng, nbta);
  k_final  <<<dim3(1, 144, 8), T256,    0, stream>>>(ws, sw, sb, out);
}